// Round 11
// baseline (1009.304 us; speedup 1.0000x reference)
//
#include <hip/hip_runtime.h>

// Problem constants: B=32, T=128, NQ=1000, NC=64, DK=128, DA=128
#define B_  32
#define T_  128
#define HBS 136   // h bf16 LDS row stride (ushorts); rows 272B, 16B-aligned

typedef __attribute__((ext_vector_type(8))) short bf16x8;
typedef __attribute__((ext_vector_type(4))) float f32x4;
typedef __attribute__((ext_vector_type(8))) unsigned short u16x8;

__device__ __forceinline__ float sigf(float x){ return __builtin_amdgcn_rcpf(1.f + __expf(-x)); }
__device__ __forceinline__ unsigned short f2b(float x){
  union { float f; unsigned int u; } v; v.f = x;
  return (unsigned short)((v.u + 0x7FFFu + ((v.u >> 16) & 1u)) >> 16);  // RNE bf16
}
__device__ __forceinline__ float b2f(unsigned short u){
  union { unsigned int x; float f; } v; v.x = ((unsigned int)u) << 16; return v.f;
}
// LDS-only barrier: skip the vmcnt(0) drain __syncthreads() emits.
__device__ __forceinline__ void bar_lds(){
  __builtin_amdgcn_sched_barrier(0);
  asm volatile("s_waitcnt lgkmcnt(0)" ::: "memory");
  __builtin_amdgcn_s_barrier();
  __builtin_amdgcn_sched_barrier(0);
}

// ---------------- stage: bf16 weight copies + a-part rowsum of W1 ----------------
__global__ __launch_bounds__(256) void stage_k(
    const float* __restrict__ W2, const float* __restrict__ W3,
    const float* __restrict__ W4, const float* __restrict__ W1,
    unsigned short* __restrict__ W2b, unsigned short* __restrict__ W3b,
    unsigned short* __restrict__ W4b, float* __restrict__ S)
{
  int i = blockIdx.x*256 + threadIdx.x;
  if (i < 128*384){ W2b[i] = f2b(W2[i]); W3b[i] = f2b(W3[i]); }
  if (i < 128*256){ W4b[i] = f2b(W4[i]); }
  if (i < 128){
    float s = 0.f;
    const float* row = W1 + (size_t)i*256 + 128;
    for (int k = 0; k < 128; ++k) s += row[k];
    S[i] = s;   // sum_k W1[i][128+k]  (a_rep constant along DA)
  }
}

// ---------------- prep: q_emb gather, qa GEMM (fp32 exact), pred[:,0]=0 ----------
__global__ __launch_bounds__(256) void prep_k(
    const int* __restrict__ qd, const float* __restrict__ ad,
    const float* __restrict__ qew, const float* __restrict__ W1,
    const float* __restrict__ b1, const float* __restrict__ S,
    float* __restrict__ oqe, float* __restrict__ oqa, float* __restrict__ pred)
{
  __shared__ float qe[16][128];
  __shared__ float w1c[128][65];
  const int tid = threadIdx.x;
  const int bt0 = blockIdx.x * 16;

  for (int i = tid; i < 16*128; i += 256){
    int r = i >> 7, d = i & 127;
    float v = qew[(size_t)qd[bt0 + r]*128 + d];
    qe[r][d] = v;
    oqe[(size_t)(bt0 + r)*128 + d] = v;
  }
  const int j = tid & 127, rh = tid >> 7;
  float accv[8];
  {
    float base = b1[j], Sj = S[j];
#pragma unroll
    for (int r = 0; r < 8; ++r) accv[r] = fmaf(ad[bt0 + rh*8 + r], Sj, base);
  }
  for (int c = 0; c < 2; ++c){
    __syncthreads();
    for (int i = tid; i < 128*64; i += 256){
      int jj = i >> 6, kk = i & 63;
      w1c[jj][kk] = W1[(size_t)jj*256 + c*64 + kk];
    }
    __syncthreads();
#pragma unroll 4
    for (int k = 0; k < 64; ++k){
      float wv = w1c[j][k];
#pragma unroll
      for (int r = 0; r < 8; ++r) accv[r] = fmaf(qe[rh*8 + r][c*64 + k], wv, accv[r]);
    }
  }
#pragma unroll
  for (int r = 0; r < 8; ++r) oqa[(size_t)(bt0 + rh*8 + r)*128 + j] = accv[r];
  if (blockIdx.x == 0 && tid < 32) pred[tid * T_] = 0.f;
}

// ---------------- l23: precompute learning part of W2/W3 GEMVs -------------------
// LI[b,t,j] = u32( bf16(b2[j] + W2[j,:256]@[qa[t-1]|qa[t]]) ,
//                  bf16(b3[j] + W3[j,:256]@[qa[t-1]|qa[t]]) )   (qa[-1]=0)
__global__ __launch_bounds__(512) void l23_k(
    const float* __restrict__ oqa,
    const unsigned short* __restrict__ W2b, const unsigned short* __restrict__ W3b,
    const float* __restrict__ b2, const float* __restrict__ b3,
    unsigned short* __restrict__ LIb)
{
  __shared__ unsigned short qab[33*136];    // rows t0-1 .. t0+31 of qa (row 0 may be zeros)
  const int blk = blockIdx.x;
  const int b = blk >> 2, t0 = (blk & 3) * 32;
  const int tid = threadIdx.x;
  const int w = tid >> 6, lane = tid & 63, g = lane >> 4, li = lane & 15;
  const int mt = w & 1, ng = w >> 1;        // m-tile (0..1), n-group (0..3)

  for (int i = tid; i < 33*128; i += 512){
    int row = i >> 7, k = i & 127;
    int tt = t0 - 1 + row;
    qab[row*136 + k] = (tt >= 0) ? f2b(oqa[((size_t)b*T_ + tt)*128 + k]) : (unsigned short)0;
  }
  __syncthreads();

  bf16x8 afr[8];
  {
    int row = mt*16 + li;
#pragma unroll
    for (int ks = 0; ks < 4; ++ks){
      afr[ks]   = *(const bf16x8*)&qab[ row   *136 + ks*32 + 8*g];  // qa[t-1]
      afr[ks+4] = *(const bf16x8*)&qab[(row+1)*136 + ks*32 + 8*g];  // qa[t]
    }
  }
  const int nt[2] = { ng, ng + 4 };
  float o2r[2][4];
#pragma unroll
  for (int m_ = 0; m_ < 2; ++m_){
    const unsigned short* Wp = m_ ? W3b : W2b;
    const float*          bp = m_ ? b3  : b2;
    f32x4 acc[2] = {{0,0,0,0},{0,0,0,0}};
#pragma unroll
    for (int u = 0; u < 2; ++u){
      int j = nt[u]*16 + li;
      const unsigned short* wr = Wp + (size_t)j*384;
#pragma unroll
      for (int ks = 0; ks < 8; ++ks){
        bf16x8 bb = *(const bf16x8*)(wr + ks*32 + 8*g);
        acc[u] = __builtin_amdgcn_mfma_f32_16x16x32_bf16(afr[ks], bb, acc[u], 0,0,0);
      }
    }
#pragma unroll
    for (int u = 0; u < 2; ++u){
      float bias = bp[nt[u]*16 + li];
      if (m_ == 0){
#pragma unroll
        for (int r = 0; r < 4; ++r) o2r[u][r] = acc[u][r] + bias;
      } else {
#pragma unroll
        for (int r = 0; r < 4; ++r){
          int t = t0 + mt*16 + g*4 + r;      // C/D: row=(lane>>4)*4+r, col=lane&15
          int j = nt[u]*16 + li;
          if (t < 127){
            unsigned int p;
            float l3f = acc[u][r] + bias;
            asm("v_cvt_pk_bf16_f32 %0, %1, %2" : "=v"(p) : "v"(o2r[u][r]), "v"(l3f));
            *(unsigned int*)&LIb[(((size_t)b*127 + t)*128 + j)*2] = p;
          }
        }
      }
    }
  }
}

// ---------------- recur: 127-step recurrence, TWO batches per block ---------------
// 1024 threads = 16 waves = 2 batch-halves of 8 waves (4 waves/SIMD, 1 block/CU).
// r9/r10 lesson: __launch_bounds__(1024[,4]) left the backend allocating for
// 8 waves/EU (VGPR cap 64 = 512-pool/8) and spilled all resident weights to
// scratch (FETCH +1.4GB, 4x time). Pin the allocation target directly with
// amdgpu_waves_per_eu(4,4): VGPR budget 512/4 = 128 >= our ~90-120 need.
struct __align__(16) SmR {
  unsigned short hb[2][64*HBS]; // bf16 h, double-buffered (MFMA A operand)
  float qe[3][64];              // qm rows, triple-buffered
  unsigned short htb[128];      // h_tilde bf16 (GEMV A operand, broadcast)
  unsigned short kcb[128];      // KC bf16 (GEMM A operand, broadcast)
  int qdl[T_];
};

__global__
__attribute__((amdgpu_flat_work_group_size(1024, 1024), amdgpu_waves_per_eu(4, 4)))
void recur_k(
    const int* __restrict__ qd, const float* __restrict__ qmx,
    const float* __restrict__ h0, const float* __restrict__ b4,
    const unsigned short* __restrict__ W2b, const unsigned short* __restrict__ W3b,
    const unsigned short* __restrict__ W4b,
    const unsigned short* __restrict__ LIb,
    float* __restrict__ H, unsigned short* __restrict__ HTg)
{
  __shared__ SmR s2[2];
  const int half = threadIdx.x >> 9;
  SmR& s = s2[half];
  const int b  = blockIdx.x*2 + half;
  const int lt = threadIdx.x & 511;
  const int w = lt >> 6, lane = lt & 63, g = lane >> 4, li = lane & 15;
  const int j = w*16 + li;

  // ---- register-resident weights (shared values, per-thread copies)
  bf16x8 w2cf[4], w3cf[4];      // W2/W3[:, 256:384] rows j (h_tilde slice)
#pragma unroll
  for (int ks = 0; ks < 4; ++ks){
    w2cf[ks] = *(const bf16x8*)(W2b + (size_t)j*384 + 256 + ks*32 + 8*g);
    w3cf[ks] = *(const bf16x8*)(W3b + (size_t)j*384 + 256 + ks*32 + 8*g);
  }
  bf16x8 w4f[8];                // W4 rows j, K=256
#pragma unroll
  for (int ks = 0; ks < 8; ++ks)
    w4f[ks] = *(const bf16x8*)(W4b + (size_t)j*256 + ks*32 + 8*g);
  const float b4v = b4[j];

  // ---- fp32 h state in registers: hreg[mt][r] = h(mt*16+g*4+r, j)
  float hreg[4][4];
#pragma unroll
  for (int mt = 0; mt < 4; ++mt)
#pragma unroll
    for (int r = 0; r < 4; ++r)
      hreg[mt][r] = h0[(mt*16 + g*4 + r)*128 + j];

  // ---- init
  for (int i = lt; i < 64*128; i += 512){
    int n = i >> 7, d = i & 127;
    float v = h0[i];
    s.hb[0][n*HBS + d] = f2b(v);
    H[(size_t)b*8192 + i] = sigf(v);   // H[0] slice, fp32 directly
  }
  if (lt < T_) s.qdl[lt] = qd[b*T_ + lt];
  __syncthreads();
  if (lt < 64){
    s.qe[0][lt] = qmx[(size_t)s.qdl[0]*64 + lt];
    s.qe[1][lt] = qmx[(size_t)s.qdl[1]*64 + lt];
  }
  __syncthreads();
  if (lt < 128){   // h_tilde0
    float acc = 0.f;
    for (int n = 0; n < 64; ++n) acc = fmaf(s.qe[0][n], h0[n*128 + lt], acc);
    s.htb[lt] = f2b(acc);
  }
  __syncthreads();

  unsigned int lv = *(const unsigned int*)&LIb[(((size_t)b*127)*128 + j)*2];
  float l2v = b2f((unsigned short)lv), l3v = b2f((unsigned short)(lv >> 16));
  f32x4 qc4[4];
#pragma unroll
  for (int mt = 0; mt < 4; ++mt) qc4[mt] = *(const f32x4*)&s.qe[0][mt*16 + g*4];

#pragma unroll 1
  for (int t = 0; t < T_-1; ++t){
    const int cur = t & 1, nxt = cur ^ 1;

    // ================= AB phase =================
    int tp1 = (t+1 < 127) ? t+1 : 126;
    unsigned int ln = *(const unsigned int*)&LIb[(((size_t)b*127 + tp1)*128 + j)*2];
    float qmxv = 0.f;
    if (lt < 64 && t+2 < T_) qmxv = qmx[(size_t)s.qdl[t+2]*64 + lt];

    // kc GEMV: 8 independent MFMAs (chain length 1)
    bf16x8 av[4];
#pragma unroll
    for (int ks = 0; ks < 4; ++ks) av[ks] = *(const bf16x8*)&s.htb[ks*32 + 8*g];
    f32x4 q2[4], q3[4];
#pragma unroll
    for (int ks = 0; ks < 4; ++ks){
      f32x4 z = {0,0,0,0};
      q2[ks] = __builtin_amdgcn_mfma_f32_16x16x32_bf16(av[ks], w2cf[ks], z, 0,0,0);
      q3[ks] = __builtin_amdgcn_mfma_f32_16x16x32_bf16(av[ks], w3cf[ks], z, 0,0,0);
    }
    // kc = sigmoid(o3) * sigmoid(2*o2), single rcp
    float o2 = (q2[0][0]+q2[1][0]) + (q2[2][0]+q2[3][0]) + l2v;
    float o3 = (q3[0][0]+q3[1][0]) + (q3[2][0]+q3[3][0]) + l3v;
    float kc = __builtin_amdgcn_rcpf((1.f + __expf(-o3)) * (1.f + __expf(-2.f*o2)));
    if (g == 0) s.kcb[j] = f2b(kc);

    // h-part GEMM (throughput work, 16 MFMAs)
    bf16x8 af[4][4];
#pragma unroll
    for (int mt = 0; mt < 4; ++mt)
#pragma unroll
      for (int ks = 0; ks < 4; ++ks)
        af[mt][ks] = *(const bf16x8*)&s.hb[cur][(mt*16 + li)*HBS + ks*32 + 8*g];
    f32x4 acc[4] = {{0,0,0,0},{0,0,0,0},{0,0,0,0},{0,0,0,0}};
#pragma unroll
    for (int ks = 0; ks < 4; ++ks)
#pragma unroll
      for (int mt = 0; mt < 4; ++mt)
        acc[mt] = __builtin_amdgcn_mfma_f32_16x16x32_bf16(af[mt][ks], w4f[ks], acc[mt], 0,0,0);

    // qn for epilogue
    f32x4 qn4[4];
#pragma unroll
    for (int mt = 0; mt < 4; ++mt)
      qn4[mt] = *(const f32x4*)&s.qe[(t+1)%3][mt*16 + g*4];
    bar_lds();                              // B1: kcb visible

    // ================= C phase =================
    bf16x8 kf[4];
#pragma unroll
    for (int ks = 0; ks < 4; ++ks) kf[ks] = *(const bf16x8*)&s.kcb[ks*32 + 8*g];
    f32x4 zk[4];
#pragma unroll
    for (int ks = 0; ks < 4; ++ks){
      f32x4 z = {0,0,0,0};
      zk[ks] = __builtin_amdgcn_mfma_f32_16x16x32_bf16(kf[ks], w4f[ks+4], z, 0,0,0);
    }
    float ack = (zk[0][0]+zk[1][0]) + (zk[2][0]+zk[3][0]);

    // coalesced RAW bf16 export of h(t) (reads hb[cur]; independent of epilogue)
    if (t >= 1){
      unsigned short* Hu = (unsigned short*)(H + ((size_t)t*B_ + b)*8192);
#pragma unroll
      for (int k = 0; k < 2; ++k){
        int c = lt + k*512;                   // ushort8 chunk in [0,1024)
        int n = c >> 4, o = (c & 15)*8;
        u16x8 hv = *(const u16x8*)&s.hb[cur][n*HBS + o];
        *(u16x8*)&Hu[c*8] = hv;
      }
    }

    float part[4];
#pragma unroll
    for (int mt = 0; mt < 4; ++mt){
      float hn[4], pp = 0.f;
#pragma unroll
      for (int r = 0; r < 4; ++r){
        float sg = sigf(acc[mt][r] + ack + b4v);
        float v = fmaf(qc4[mt][r], kc, sg*hreg[mt][r]);
        hreg[mt][r] = v; hn[r] = v;
        pp = fmaf(qn4[mt][r], v, pp);
      }
      part[mt] = pp;
      unsigned int p01, p23;
      asm("v_cvt_pk_bf16_f32 %0, %1, %2" : "=v"(p01) : "v"(hn[0]), "v"(hn[1]));
      asm("v_cvt_pk_bf16_f32 %0, %1, %2" : "=v"(p23) : "v"(hn[2]), "v"(hn[3]));
      int n0 = mt*16 + g*4;                  // C/D: row=(lane>>4)*4+r, col=lane&15
      unsigned short* bp_ = &s.hb[nxt][n0*HBS + j];
      bp_[0]       = (unsigned short)p01;
      bp_[HBS]     = (unsigned short)(p01 >> 16);
      bp_[2*HBS]   = (unsigned short)p23;
      bp_[3*HBS]   = (unsigned short)(p23 >> 16);
    }
    float prt = (part[0]+part[1]) + (part[2]+part[3]);
    prt += __shfl_xor(prt, 16);
    prt += __shfl_xor(prt, 32);
    if (g == 0){
      unsigned short hb16 = f2b(prt);
      s.htb[j] = hb16;
      HTg[((size_t)b*T_ + t + 1)*128 + j] = hb16;
    }
    if (lt < 64 && t+2 < T_) s.qe[(t+2)%3][lt] = qmxv;
    lv = ln;
    l2v = b2f((unsigned short)lv); l3v = b2f((unsigned short)(lv >> 16));
#pragma unroll
    for (int mt = 0; mt < 4; ++mt) qc4[mt] = qn4[mt];
    bar_lds();                              // B2: htb/hb[nxt]/qe visible
  }
}

// ---------------- post: ypost (blocks 0..126) + hexp (blocks 127..4158) ----------
__global__ __launch_bounds__(256) void post_k(
    const float* __restrict__ oqe, const unsigned short* __restrict__ HT,
    const float* __restrict__ W5, const float* __restrict__ b5,
    float* __restrict__ pred, float* __restrict__ H)
{
  __shared__ float X[32][256];
  __shared__ float w5c[128][33];
  const int tid = threadIdx.x;

  if ((int)blockIdx.x >= 127){
    // ---- hexp role: in-place bf16 -> sigmoid(f32) expansion of one H slice
    const int tb = blockIdx.x - 127;
    const int t  = (tb >> 5) + 1, b = tb & 31;
    float* Hs = H + ((size_t)t*B_ + b)*8192;
    const unsigned short* Hu = (const unsigned short*)Hs;
    u16x8 v[4];
#pragma unroll
    for (int k = 0; k < 4; ++k) v[k] = *(const u16x8*)&Hu[(k*256 + tid)*8];
    __syncthreads();
#pragma unroll
    for (int k = 0; k < 4; ++k){
      int c = k*256 + tid;
      f32x4 lo, hi;
      lo[0]=sigf(b2f(v[k][0])); lo[1]=sigf(b2f(v[k][1]));
      lo[2]=sigf(b2f(v[k][2])); lo[3]=sigf(b2f(v[k][3]));
      hi[0]=sigf(b2f(v[k][4])); hi[1]=sigf(b2f(v[k][5]));
      hi[2]=sigf(b2f(v[k][6])); hi[3]=sigf(b2f(v[k][7]));
      *(f32x4*)&Hs[c*8]     = lo;
      *(f32x4*)&Hs[c*8 + 4] = hi;
    }
    return;
  }

  // ---- ypost role: y GEMV over all b for tau = blockIdx.x + 1
  const int tau = blockIdx.x + 1;
  for (int i = tid; i < 32*128; i += 256){
    int bb = i >> 7, k = i & 127;
    X[bb][k] = oqe[((size_t)bb*T_ + tau)*128 + k];
    X[bb][128 + k] = b2f(HT[((size_t)bb*T_ + tau)*128 + k]);
  }
  const int j = tid & 127, rh = tid >> 7;
  float acc[16];
  float base = b5[j];
#pragma unroll
  for (int r = 0; r < 16; ++r) acc[r] = base;
  for (int c = 0; c < 8; ++c){
    __syncthreads();
    for (int i = tid; i < 128*32; i += 256){
      int jj = i >> 5, kk = i & 31;
      w5c[jj][kk] = W5[(size_t)jj*256 + c*32 + kk];
    }
    __syncthreads();
#pragma unroll 8
    for (int k = 0; k < 32; ++k){
      float wv = w5c[j][k];
#pragma unroll
      for (int r = 0; r < 16; ++r) acc[r] = fmaf(X[rh*16 + r][c*32 + k], wv, acc[r]);
    }
  }
  __syncthreads();
#pragma unroll
  for (int r = 0; r < 16; ++r) X[rh*16 + r][j] = sigf(acc[r]);
  __syncthreads();
  if (tid < 32){
    float ssum = 0.f;
    for (int k = 0; k < 128; ++k) ssum += X[tid][k];
    pred[tid*T_ + tau] = ssum * (1.f/128.f);
  }
}

extern "C" void kernel_launch(void* const* d_in, const int* in_sizes, int n_in,
                              void* d_out, int out_size, void* d_ws, size_t ws_size,
                              hipStream_t stream)
{
  const int*   qd  = (const int*)  d_in[0];
  const float* ad  = (const float*)d_in[1];
  const float* qmx = (const float*)d_in[2];
  const float* qew = (const float*)d_in[3];
  const float* W1  = (const float*)d_in[4];
  const float* b1  = (const float*)d_in[5];
  const float* W2  = (const float*)d_in[6];
  const float* b2  = (const float*)d_in[7];
  const float* W3  = (const float*)d_in[8];
  const float* b3  = (const float*)d_in[9];
  const float* W4  = (const float*)d_in[10];
  const float* b4  = (const float*)d_in[11];
  const float* W5  = (const float*)d_in[12];
  const float* b5  = (const float*)d_in[13];
  const float* h0  = (const float*)d_in[14];

  float* H    = (float*)d_out;                         // [127][32][64][128]
  float* pred = H    + (size_t)127*32*64*128;          // [32][128]
  float* oqe  = pred + (size_t)32*128;                 // [32][128][128]
  float* oqa  = oqe  + (size_t)32*128*128;             // [32][128][128]

  unsigned short* W2b = (unsigned short*)d_ws;         // [128][384] bf16
  unsigned short* W3b = W2b + 128*384;                 // [128][384] bf16
  unsigned short* W4b = W3b + 128*384;                 // [128][256] bf16
  unsigned short* HTg = W4b + 128*256;                 // [32][128][128] bf16 h_tilde
  unsigned short* LIb = HTg + (size_t)32*128*128;      // [32][127][128][2] bf16 (l2,l3)
  float*          S   = (float*)(LIb + (size_t)32*127*128*2);  // [128]

  stage_k<<<192, 256, 0, stream>>>(W2, W3, W4, W1, W2b, W3b, W4b, S);
  prep_k <<<256, 256, 0, stream>>>(qd, ad, qew, W1, b1, S, oqe, oqa, pred);
  l23_k  <<<128, 512, 0, stream>>>(oqa, W2b, W3b, b2, b3, LIb);
  recur_k<<<16,  1024, 0, stream>>>(qd, qmx, h0, b4, W2b, W3b, W4b,
                                    LIb, H, HTg);
  post_k <<<127 + 126*32, 256, 0, stream>>>(oqe, HTg, W5, b5, pred, H);
}

// Round 12
// 576.670 us; speedup vs baseline: 1.7502x; 1.7502x over previous
//
#include <hip/hip_runtime.h>

// Problem constants: B=32, T=128, NQ=1000, NC=64, DK=128, DA=128
#define B_  32
#define T_  128
#define HBS 136   // h bf16 LDS row stride (ushorts); rows 272B, 16B-aligned

typedef __attribute__((ext_vector_type(8))) short bf16x8;
typedef __attribute__((ext_vector_type(4))) float f32x4;
typedef __attribute__((ext_vector_type(8))) unsigned short u16x8;

__device__ __forceinline__ float sigf(float x){ return __builtin_amdgcn_rcpf(1.f + __expf(-x)); }
__device__ __forceinline__ unsigned short f2b(float x){
  union { float f; unsigned int u; } v; v.f = x;
  return (unsigned short)((v.u + 0x7FFFu + ((v.u >> 16) & 1u)) >> 16);  // RNE bf16
}
__device__ __forceinline__ float b2f(unsigned short u){
  union { unsigned int x; float f; } v; v.x = ((unsigned int)u) << 16; return v.f;
}
// LDS-only barrier: skip the vmcnt(0) drain __syncthreads() emits.
__device__ __forceinline__ void bar_lds(){
  __builtin_amdgcn_sched_barrier(0);
  asm volatile("s_waitcnt lgkmcnt(0)" ::: "memory");
  __builtin_amdgcn_s_barrier();
  __builtin_amdgcn_sched_barrier(0);
}

// ---------------- stage: bf16 weight copies + a-part rowsum of W1 ----------------
__global__ __launch_bounds__(256) void stage_k(
    const float* __restrict__ W2, const float* __restrict__ W3,
    const float* __restrict__ W4, const float* __restrict__ W1,
    unsigned short* __restrict__ W2b, unsigned short* __restrict__ W3b,
    unsigned short* __restrict__ W4b, float* __restrict__ S)
{
  int i = blockIdx.x*256 + threadIdx.x;
  if (i < 128*384){ W2b[i] = f2b(W2[i]); W3b[i] = f2b(W3[i]); }
  if (i < 128*256){ W4b[i] = f2b(W4[i]); }
  if (i < 128){
    float s = 0.f;
    const float* row = W1 + (size_t)i*256 + 128;
    for (int k = 0; k < 128; ++k) s += row[k];
    S[i] = s;   // sum_k W1[i][128+k]  (a_rep constant along DA)
  }
}

// ---------------- prep: q_emb gather, qa GEMM (fp32 exact), pred[:,0]=0 ----------
__global__ __launch_bounds__(256) void prep_k(
    const int* __restrict__ qd, const float* __restrict__ ad,
    const float* __restrict__ qew, const float* __restrict__ W1,
    const float* __restrict__ b1, const float* __restrict__ S,
    float* __restrict__ oqe, float* __restrict__ oqa, float* __restrict__ pred)
{
  __shared__ float qe[16][128];
  __shared__ float w1c[128][65];
  const int tid = threadIdx.x;
  const int bt0 = blockIdx.x * 16;

  for (int i = tid; i < 16*128; i += 256){
    int r = i >> 7, d = i & 127;
    float v = qew[(size_t)qd[bt0 + r]*128 + d];
    qe[r][d] = v;
    oqe[(size_t)(bt0 + r)*128 + d] = v;
  }
  const int j = tid & 127, rh = tid >> 7;
  float accv[8];
  {
    float base = b1[j], Sj = S[j];
#pragma unroll
    for (int r = 0; r < 8; ++r) accv[r] = fmaf(ad[bt0 + rh*8 + r], Sj, base);
  }
  for (int c = 0; c < 2; ++c){
    __syncthreads();
    for (int i = tid; i < 128*64; i += 256){
      int jj = i >> 6, kk = i & 63;
      w1c[jj][kk] = W1[(size_t)jj*256 + c*64 + kk];
    }
    __syncthreads();
#pragma unroll 4
    for (int k = 0; k < 64; ++k){
      float wv = w1c[j][k];
#pragma unroll
      for (int r = 0; r < 8; ++r) accv[r] = fmaf(qe[rh*8 + r][c*64 + k], wv, accv[r]);
    }
  }
#pragma unroll
  for (int r = 0; r < 8; ++r) oqa[(size_t)(bt0 + rh*8 + r)*128 + j] = accv[r];
  if (blockIdx.x == 0 && tid < 32) pred[tid * T_] = 0.f;
}

// ---------------- l23: precompute learning part of W2/W3 GEMVs -------------------
// LI[b,t,j] = u32( bf16(b2[j] + W2[j,:256]@[qa[t-1]|qa[t]]) ,
//                  bf16(b3[j] + W3[j,:256]@[qa[t-1]|qa[t]]) )   (qa[-1]=0)
__global__ __launch_bounds__(512) void l23_k(
    const float* __restrict__ oqa,
    const unsigned short* __restrict__ W2b, const unsigned short* __restrict__ W3b,
    const float* __restrict__ b2, const float* __restrict__ b3,
    unsigned short* __restrict__ LIb)
{
  __shared__ unsigned short qab[33*136];    // rows t0-1 .. t0+31 of qa (row 0 may be zeros)
  const int blk = blockIdx.x;
  const int b = blk >> 2, t0 = (blk & 3) * 32;
  const int tid = threadIdx.x;
  const int w = tid >> 6, lane = tid & 63, g = lane >> 4, li = lane & 15;
  const int mt = w & 1, ng = w >> 1;        // m-tile (0..1), n-group (0..3)

  for (int i = tid; i < 33*128; i += 512){
    int row = i >> 7, k = i & 127;
    int tt = t0 - 1 + row;
    qab[row*136 + k] = (tt >= 0) ? f2b(oqa[((size_t)b*T_ + tt)*128 + k]) : (unsigned short)0;
  }
  __syncthreads();

  bf16x8 afr[8];
  {
    int row = mt*16 + li;
#pragma unroll
    for (int ks = 0; ks < 4; ++ks){
      afr[ks]   = *(const bf16x8*)&qab[ row   *136 + ks*32 + 8*g];  // qa[t-1]
      afr[ks+4] = *(const bf16x8*)&qab[(row+1)*136 + ks*32 + 8*g];  // qa[t]
    }
  }
  const int nt[2] = { ng, ng + 4 };
  float o2r[2][4];
#pragma unroll
  for (int m_ = 0; m_ < 2; ++m_){
    const unsigned short* Wp = m_ ? W3b : W2b;
    const float*          bp = m_ ? b3  : b2;
    f32x4 acc[2] = {{0,0,0,0},{0,0,0,0}};
#pragma unroll
    for (int u = 0; u < 2; ++u){
      int j = nt[u]*16 + li;
      const unsigned short* wr = Wp + (size_t)j*384;
#pragma unroll
      for (int ks = 0; ks < 8; ++ks){
        bf16x8 bb = *(const bf16x8*)(wr + ks*32 + 8*g);
        acc[u] = __builtin_amdgcn_mfma_f32_16x16x32_bf16(afr[ks], bb, acc[u], 0,0,0);
      }
    }
#pragma unroll
    for (int u = 0; u < 2; ++u){
      float bias = bp[nt[u]*16 + li];
      if (m_ == 0){
#pragma unroll
        for (int r = 0; r < 4; ++r) o2r[u][r] = acc[u][r] + bias;
      } else {
#pragma unroll
        for (int r = 0; r < 4; ++r){
          int t = t0 + mt*16 + g*4 + r;      // C/D: row=(lane>>4)*4+r, col=lane&15
          int j = nt[u]*16 + li;
          if (t < 127){
            unsigned int p;
            float l3f = acc[u][r] + bias;
            asm("v_cvt_pk_bf16_f32 %0, %1, %2" : "=v"(p) : "v"(o2r[u][r]), "v"(l3f));
            *(unsigned int*)&LIb[(((size_t)b*127 + t)*128 + j)*2] = p;
          }
        }
      }
    }
  }
}

// ---------------- recur: 127-step recurrence, TWO batches per 512-thread block ----
// Waves 0-3 = batch 2*blk, waves 4-7 = batch 2*blk+1. Each wave owns 32 output
// cols (2 j-tiles): halves per-batch LDS A-fragment traffic vs 8-wave map, so
// 2 batches/CU cost the same LDS BW as r8's 1. 512 threads keeps the VGPR cap
// at 256 (the 1024-thread kernel was hard-capped at 64 VGPR -> spilled, r9-r11).
// kc-half of W4 (w4k) is per-step global-prefetched (L2) to stay under ~200 VGPR.
struct __align__(16) SmR {
  unsigned short hb[2][64*HBS]; // bf16 h, double-buffered (MFMA A operand)
  float qe[3][64];              // qm rows, triple-buffered
  unsigned short htb[128];      // h_tilde bf16 (GEMV A operand, broadcast)
  unsigned short kcb[128];      // KC bf16 (GEMM A operand, broadcast)
  int qdl[T_];
};

__global__ __launch_bounds__(512, 2) void recur_k(
    const int* __restrict__ qd, const float* __restrict__ qmx,
    const float* __restrict__ h0, const float* __restrict__ b4,
    const unsigned short* __restrict__ W2b, const unsigned short* __restrict__ W3b,
    const unsigned short* __restrict__ W4b,
    const unsigned short* __restrict__ LIb,
    float* __restrict__ H, unsigned short* __restrict__ HTg)
{
  __shared__ SmR s2[2];
  const int lt   = threadIdx.x;
  const int half = lt >> 8;            // which batch of this block
  SmR& s = s2[half];
  const int b   = blockIdx.x*2 + half;
  const int ltl = lt & 255;            // thread within half
  const int lane = lt & 63, g = lane >> 4, li = lane & 15;
  const int wb = (lt >> 6) & 3;        // wave within half
  const int jc[2] = { wb*32 + li, wb*32 + 16 + li };

  // ---- register-resident weights: 2 j-tiles per wave
  bf16x8 w2cf[2][4], w3cf[2][4], w4f[2][4];
  float b4v[2];
#pragma unroll
  for (int u = 0; u < 2; ++u){
#pragma unroll
    for (int ks = 0; ks < 4; ++ks){
      w2cf[u][ks] = *(const bf16x8*)(W2b + (size_t)jc[u]*384 + 256 + ks*32 + 8*g);
      w3cf[u][ks] = *(const bf16x8*)(W3b + (size_t)jc[u]*384 + 256 + ks*32 + 8*g);
      w4f[u][ks]  = *(const bf16x8*)(W4b + (size_t)jc[u]*256 + ks*32 + 8*g);  // h-part (k<128)
    }
    b4v[u] = b4[jc[u]];
  }

  // ---- fp32 h state in registers: hreg[u][mt][r] = h(mt*16+g*4+r, jc[u])
  float hreg[2][4][4];
#pragma unroll
  for (int u = 0; u < 2; ++u)
#pragma unroll
    for (int mt = 0; mt < 4; ++mt)
#pragma unroll
      for (int r = 0; r < 4; ++r)
        hreg[u][mt][r] = h0[(mt*16 + g*4 + r)*128 + jc[u]];

  // ---- init (each half inits its own batch)
  for (int i = ltl; i < 64*128; i += 256){
    int n = i >> 7, d = i & 127;
    float v = h0[i];
    s.hb[0][n*HBS + d] = f2b(v);
    H[(size_t)b*8192 + i] = sigf(v);   // H[0] slice, fp32 directly
  }
  if (ltl < T_) s.qdl[ltl] = qd[b*T_ + ltl];
  __syncthreads();
  if (ltl < 64){
    s.qe[0][ltl] = qmx[(size_t)s.qdl[0]*64 + ltl];
    s.qe[1][ltl] = qmx[(size_t)s.qdl[1]*64 + ltl];
  }
  __syncthreads();
  if (ltl < 128){   // h_tilde0
    float acc = 0.f;
    for (int n = 0; n < 64; ++n) acc = fmaf(s.qe[0][n], h0[n*128 + ltl], acc);
    s.htb[ltl] = f2b(acc);
  }
  __syncthreads();

  unsigned int lv[2];
#pragma unroll
  for (int u = 0; u < 2; ++u)
    lv[u] = *(const unsigned int*)&LIb[(((size_t)b*127)*128 + jc[u])*2];

#pragma unroll 1
  for (int t = 0; t < T_-1; ++t){
    const int cur = t & 1, nxt = cur ^ 1;

    // ================= AB phase =================
    int tp1 = (t+1 < 127) ? t+1 : 126;
    unsigned int ln[2];
    bf16x8 w4k[2][4];                  // kc-part of W4 (k in [128,256)), L2-resident stream
#pragma unroll
    for (int u = 0; u < 2; ++u){
      ln[u] = *(const unsigned int*)&LIb[(((size_t)b*127 + tp1)*128 + jc[u])*2];
#pragma unroll
      for (int ks = 0; ks < 4; ++ks)
        w4k[u][ks] = *(const bf16x8*)(W4b + (size_t)jc[u]*256 + 128 + ks*32 + 8*g);
    }
    float qmxv = 0.f;
    if (ltl < 64 && t+2 < T_) qmxv = qmx[(size_t)s.qdl[t+2]*64 + ltl];

    // kc GEMVs for both j-tiles (16 independent MFMAs)
    bf16x8 av[4];
#pragma unroll
    for (int ks = 0; ks < 4; ++ks) av[ks] = *(const bf16x8*)&s.htb[ks*32 + 8*g];
    float kc2[2];
#pragma unroll
    for (int u = 0; u < 2; ++u){
      f32x4 q2[4], q3[4];
#pragma unroll
      for (int ks = 0; ks < 4; ++ks){
        f32x4 z = {0,0,0,0};
        q2[ks] = __builtin_amdgcn_mfma_f32_16x16x32_bf16(av[ks], w2cf[u][ks], z, 0,0,0);
        q3[ks] = __builtin_amdgcn_mfma_f32_16x16x32_bf16(av[ks], w3cf[u][ks], z, 0,0,0);
      }
      float o2 = (q2[0][0]+q2[1][0]) + (q2[2][0]+q2[3][0]) + b2f((unsigned short)lv[u]);
      float o3 = (q3[0][0]+q3[1][0]) + (q3[2][0]+q3[3][0]) + b2f((unsigned short)(lv[u] >> 16));
      kc2[u] = __builtin_amdgcn_rcpf((1.f + __expf(-o3)) * (1.f + __expf(-2.f*o2)));
      if (g == 0) s.kcb[jc[u]] = f2b(kc2[u]);
    }
    bar_lds();                              // B1: kcb visible

    // ================= C phase =================
    bf16x8 kf[4];
#pragma unroll
    for (int ks = 0; ks < 4; ++ks) kf[ks] = *(const bf16x8*)&s.kcb[ks*32 + 8*g];
    float ack[2];
#pragma unroll
    for (int u = 0; u < 2; ++u){
      f32x4 zk[4];
#pragma unroll
      for (int ks = 0; ks < 4; ++ks){
        f32x4 z = {0,0,0,0};
        zk[ks] = __builtin_amdgcn_mfma_f32_16x16x32_bf16(kf[ks], w4k[u][ks], z, 0,0,0);
      }
      ack[u] = (zk[0][0]+zk[1][0]) + (zk[2][0]+zk[3][0]);
    }

    // h-part GEMM: af loaded once, feeds both j-tiles (32 MFMAs)
    f32x4 acc[2][4] = {{{0,0,0,0},{0,0,0,0},{0,0,0,0},{0,0,0,0}},
                       {{0,0,0,0},{0,0,0,0},{0,0,0,0},{0,0,0,0}}};
#pragma unroll
    for (int ks = 0; ks < 4; ++ks)
#pragma unroll
      for (int mt = 0; mt < 4; ++mt){
        bf16x8 af = *(const bf16x8*)&s.hb[cur][(mt*16 + li)*HBS + ks*32 + 8*g];
        acc[0][mt] = __builtin_amdgcn_mfma_f32_16x16x32_bf16(af, w4f[0][ks], acc[0][mt], 0,0,0);
        acc[1][mt] = __builtin_amdgcn_mfma_f32_16x16x32_bf16(af, w4f[1][ks], acc[1][mt], 0,0,0);
      }

    // coalesced RAW bf16 export of h(t) (reads hb[cur]; independent of epilogue)
    if (t >= 1){
      unsigned short* Hu = (unsigned short*)(H + ((size_t)t*B_ + b)*8192);
#pragma unroll
      for (int k = 0; k < 4; ++k){
        int c = ltl + k*256;                  // ushort8 chunk in [0,1024)
        int n = c >> 4, o = (c & 15)*8;
        u16x8 hv = *(const u16x8*)&s.hb[cur][n*HBS + o];
        *(u16x8*)&Hu[c*8] = hv;
      }
    }

    float part[2] = {0.f, 0.f};
#pragma unroll
    for (int mt = 0; mt < 4; ++mt){
      f32x4 qcv = *(const f32x4*)&s.qe[t%3][mt*16 + g*4];
      f32x4 qnv = *(const f32x4*)&s.qe[(t+1)%3][mt*16 + g*4];
#pragma unroll
      for (int u = 0; u < 2; ++u){
        float hn[4];
#pragma unroll
        for (int r = 0; r < 4; ++r){
          float sg = sigf(acc[u][mt][r] + ack[u] + b4v[u]);
          float v = fmaf(qcv[r], kc2[u], sg*hreg[u][mt][r]);
          hreg[u][mt][r] = v; hn[r] = v;
          part[u] = fmaf(qnv[r], v, part[u]);
        }
        unsigned int p01, p23;
        asm("v_cvt_pk_bf16_f32 %0, %1, %2" : "=v"(p01) : "v"(hn[0]), "v"(hn[1]));
        asm("v_cvt_pk_bf16_f32 %0, %1, %2" : "=v"(p23) : "v"(hn[2]), "v"(hn[3]));
        int n0 = mt*16 + g*4;                // C/D: row=(lane>>4)*4+r, col=lane&15
        unsigned short* bp_ = &s.hb[nxt][n0*HBS + jc[u]];
        bp_[0]     = (unsigned short)p01;
        bp_[HBS]   = (unsigned short)(p01 >> 16);
        bp_[2*HBS] = (unsigned short)p23;
        bp_[3*HBS] = (unsigned short)(p23 >> 16);
      }
    }
#pragma unroll
    for (int u = 0; u < 2; ++u){
      float prt = part[u];
      prt += __shfl_xor(prt, 16);
      prt += __shfl_xor(prt, 32);
      if (g == 0){
        unsigned short hb16 = f2b(prt);
        s.htb[jc[u]] = hb16;
        HTg[((size_t)b*T_ + t + 1)*128 + jc[u]] = hb16;
      }
    }
    if (ltl < 64 && t+2 < T_) s.qe[(t+2)%3][ltl] = qmxv;
    lv[0] = ln[0]; lv[1] = ln[1];
    bar_lds();                              // B2: htb/hb[nxt]/qe visible
  }
}

// ---------------- post: ypost (blocks 0..126) + hexp (blocks 127..4158) ----------
__global__ __launch_bounds__(256) void post_k(
    const float* __restrict__ oqe, const unsigned short* __restrict__ HT,
    const float* __restrict__ W5, const float* __restrict__ b5,
    float* __restrict__ pred, float* __restrict__ H)
{
  __shared__ float X[32][256];
  __shared__ float w5c[128][33];
  const int tid = threadIdx.x;

  if ((int)blockIdx.x >= 127){
    // ---- hexp role: in-place bf16 -> sigmoid(f32) expansion of one H slice
    const int tb = blockIdx.x - 127;
    const int t  = (tb >> 5) + 1, b = tb & 31;
    float* Hs = H + ((size_t)t*B_ + b)*8192;
    const unsigned short* Hu = (const unsigned short*)Hs;
    u16x8 v[4];
#pragma unroll
    for (int k = 0; k < 4; ++k) v[k] = *(const u16x8*)&Hu[(k*256 + tid)*8];
    __syncthreads();
#pragma unroll
    for (int k = 0; k < 4; ++k){
      int c = k*256 + tid;
      f32x4 lo, hi;
      lo[0]=sigf(b2f(v[k][0])); lo[1]=sigf(b2f(v[k][1]));
      lo[2]=sigf(b2f(v[k][2])); lo[3]=sigf(b2f(v[k][3]));
      hi[0]=sigf(b2f(v[k][4])); hi[1]=sigf(b2f(v[k][5]));
      hi[2]=sigf(b2f(v[k][6])); hi[3]=sigf(b2f(v[k][7]));
      *(f32x4*)&Hs[c*8]     = lo;
      *(f32x4*)&Hs[c*8 + 4] = hi;
    }
    return;
  }

  // ---- ypost role: y GEMV over all b for tau = blockIdx.x + 1
  const int tau = blockIdx.x + 1;
  for (int i = tid; i < 32*128; i += 256){
    int bb = i >> 7, k = i & 127;
    X[bb][k] = oqe[((size_t)bb*T_ + tau)*128 + k];
    X[bb][128 + k] = b2f(HT[((size_t)bb*T_ + tau)*128 + k]);
  }
  const int j = tid & 127, rh = tid >> 7;
  float acc[16];
  float base = b5[j];
#pragma unroll
  for (int r = 0; r < 16; ++r) acc[r] = base;
  for (int c = 0; c < 8; ++c){
    __syncthreads();
    for (int i = tid; i < 128*32; i += 256){
      int jj = i >> 5, kk = i & 31;
      w5c[jj][kk] = W5[(size_t)jj*256 + c*32 + kk];
    }
    __syncthreads();
#pragma unroll 8
    for (int k = 0; k < 32; ++k){
      float wv = w5c[j][k];
#pragma unroll
      for (int r = 0; r < 16; ++r) acc[r] = fmaf(X[rh*16 + r][c*32 + k], wv, acc[r]);
    }
  }
  __syncthreads();
#pragma unroll
  for (int r = 0; r < 16; ++r) X[rh*16 + r][j] = sigf(acc[r]);
  __syncthreads();
  if (tid < 32){
    float ssum = 0.f;
    for (int k = 0; k < 128; ++k) ssum += X[tid][k];
    pred[tid*T_ + tau] = ssum * (1.f/128.f);
  }
}

extern "C" void kernel_launch(void* const* d_in, const int* in_sizes, int n_in,
                              void* d_out, int out_size, void* d_ws, size_t ws_size,
                              hipStream_t stream)
{
  const int*   qd  = (const int*)  d_in[0];
  const float* ad  = (const float*)d_in[1];
  const float* qmx = (const float*)d_in[2];
  const float* qew = (const float*)d_in[3];
  const float* W1  = (const float*)d_in[4];
  const float* b1  = (const float*)d_in[5];
  const float* W2  = (const float*)d_in[6];
  const float* b2  = (const float*)d_in[7];
  const float* W3  = (const float*)d_in[8];
  const float* b3  = (const float*)d_in[9];
  const float* W4  = (const float*)d_in[10];
  const float* b4  = (const float*)d_in[11];
  const float* W5  = (const float*)d_in[12];
  const float* b5  = (const float*)d_in[13];
  const float* h0  = (const float*)d_in[14];

  float* H    = (float*)d_out;                         // [127][32][64][128]
  float* pred = H    + (size_t)127*32*64*128;          // [32][128]
  float* oqe  = pred + (size_t)32*128;                 // [32][128][128]
  float* oqa  = oqe  + (size_t)32*128*128;             // [32][128][128]

  unsigned short* W2b = (unsigned short*)d_ws;         // [128][384] bf16
  unsigned short* W3b = W2b + 128*384;                 // [128][384] bf16
  unsigned short* W4b = W3b + 128*384;                 // [128][256] bf16
  unsigned short* HTg = W4b + 128*256;                 // [32][128][128] bf16 h_tilde
  unsigned short* LIb = HTg + (size_t)32*128*128;      // [32][127][128][2] bf16 (l2,l3)
  float*          S   = (float*)(LIb + (size_t)32*127*128*2);  // [128]

  stage_k<<<192, 256, 0, stream>>>(W2, W3, W4, W1, W2b, W3b, W4b, S);
  prep_k <<<256, 256, 0, stream>>>(qd, ad, qew, W1, b1, S, oqe, oqa, pred);
  l23_k  <<<128, 512, 0, stream>>>(oqa, W2b, W3b, b2, b3, LIb);
  recur_k<<<16,  512, 0, stream>>>(qd, qmx, h0, b4, W2b, W3b, W4b,
                                   LIb, H, HTg);
  post_k <<<127 + 126*32, 256, 0, stream>>>(oqe, HTg, W5, b5, pred, H);
}